// Round 6
// baseline (5041.787 us; speedup 1.0000x reference)
//
#include <hip/hip_runtime.h>
#include <hip/hip_bf16.h>
#include <hip/hip_cooperative_groups.h>
#include <math.h>

namespace cg = cooperative_groups;

#define XKP 1216

typedef unsigned short u16;
typedef short bf16x8 __attribute__((ext_vector_type(8)));
typedef float f32x4 __attribute__((ext_vector_type(4)));

static __device__ __forceinline__ float sigmoidf_(float x){ return 1.f/(1.f+expf(-x)); }
static __device__ __forceinline__ u16 f2bf(float x){ __hip_bfloat16 h = __float2bfloat16(x); return *reinterpret_cast<u16*>(&h); }
static __device__ __forceinline__ float bf2f(u16 u){ __hip_bfloat16 h; *reinterpret_cast<u16*>(&h) = u; return __bfloat162float(h); }

// ---------- generic 32x32 tiled transpose: in[R][C] -> out[C][R] ----------
__global__ __launch_bounds__(256) void k_transpose(const float* __restrict__ in,
                                                   float* __restrict__ out, int R, int C) {
  __shared__ float tile[32][33];
  int c0 = blockIdx.x * 32, r0 = blockIdx.y * 32;
  int tx = threadIdx.x & 31, ty = threadIdx.x >> 5;
  for (int i = 0; i < 32; i += 8) {
    int r = r0 + ty + i, c = c0 + tx;
    tile[ty + i][tx] = (r < R && c < C) ? in[(size_t)r * C + c] : 0.f;
  }
  __syncthreads();
  for (int i = 0; i < 32; i += 8) {
    int c = c0 + ty + i, r = r0 + tx;
    if (c < C && r < R) out[(size_t)c * R + r] = tile[tx][ty + i];
  }
}

// ---------- fp32 -> bf16 elementwise ----------
__global__ __launch_bounds__(256) void k_cvt(const float* __restrict__ in,
                                             u16* __restrict__ out, int n) {
  for (int i = blockIdx.x * 256 + threadIdx.x; i < n; i += gridDim.x * 256)
    out[i] = f2bf(in[i]);
}

// ---------- Wcat split hi/lo, gate-interleaved: row n'=d*4+g <- j=g*512+d ----------
__global__ __launch_bounds__(256) void k_wcat_split(const float* __restrict__ W_ih,
                                                    const float* __restrict__ W_hh,
                                                    u16* __restrict__ Whi,
                                                    u16* __restrict__ Wlo) {
  int np = blockIdx.x;               // 0..2047
  int d = np >> 2, g = np & 3;
  int j = g * 512 + d;               // torch gate row
  for (int c = threadIdx.x; c < XKP; c += 256) {
    float v;
    if (c < 684)        v = W_ih[(size_t)j * 684 + c];
    else if (c < 1196)  v = W_hh[(size_t)j * 512 + (c - 684)];
    else                v = 0.f;
    u16 hi = f2bf(v);
    u16 lo = f2bf(v - bf2f(hi));
    Whi[(size_t)np * XKP + c] = hi;
    Wlo[(size_t)np * XKP + c] = lo;
  }
}

// ---------- objectness mask + top-16 order stat + enc mean ----------
__global__ __launch_bounds__(128) void k_mask(const float* __restrict__ objs,
                                              const float* __restrict__ rcl,
                                              const float* __restrict__ avx,
                                              const float* __restrict__ enc,
                                              float* __restrict__ maskf,
                                              float* __restrict__ encmean,
                                              float* __restrict__ out_mask) {
  int b = blockIdx.x, k = threadIdx.x;
  __shared__ float dsh[128];
  __shared__ float maxd;
  float s0 = objs[(size_t)(b * 128 + k) * 2 + 0];
  float s1 = objs[(size_t)(b * 128 + k) * 2 + 1];
  float mx = fmaxf(s0, s1);
  float e0 = expf(s0 - mx), e1 = expf(s1 - mx);
  float p  = e1 / (e0 + e1);
  bool om  = p > 0.75f;
  float dx = rcl[b * 3 + 0] - avx[(size_t)(b * 128 + k) * 3 + 0];
  float dy = rcl[b * 3 + 1] - avx[(size_t)(b * 128 + k) * 3 + 1];
  float dz = rcl[b * 3 + 2] - avx[(size_t)(b * 128 + k) * 3 + 2];
  float dist = sqrtf(dx * dx + dy * dy + dz * dz);
  float dm = om ? dist : INFINITY;
  dsh[k] = dm;
  __syncthreads();
  float v = dm; int clt = 0, cle = 0;
  for (int j = 0; j < 128; j++) { float o = dsh[j]; clt += (o < v); cle += (o <= v); }
  if (clt < 16 && cle >= 16) maxd = v;
  __syncthreads();
  bool msk = om && (dm <= maxd);
  maskf[b * 128 + k]    = msk ? 1.f : 0.f;
  out_mask[b * 128 + k] = msk ? 1.f : 0.f;
  float s = 0.f;
  for (int kk = 0; kk < 128; kk++) s += enc[(size_t)(b * 128 + kk) * 128 + k];
  encmean[b * 128 + k] = s * (1.f / 128.f);
}

// ---------- h0/c0 init ----------
__global__ __launch_bounds__(512) void k_init(const float* __restrict__ encm,
                                              const float* __restrict__ rof,
                                              const float* __restrict__ wihT,
                                              const float* __restrict__ wicT,
                                              const float* __restrict__ bh,
                                              const float* __restrict__ bc,
                                              float* __restrict__ h, float* __restrict__ c,
                                              u16* __restrict__ hb16) {
  int b = blockIdx.x, d = threadIdx.x;
  __shared__ float xin[384];
  if (d < 128) xin[d] = encm[b * 128 + d];
  else if (d < 384) xin[d] = rof[(size_t)b * 256 + (d - 128)];
  __syncthreads();
  float ah = bh[d], ac = bc[d];
  for (int i = 0; i < 384; i++) {
    float x = xin[i];
    ah += x * wihT[(size_t)i * 512 + d];
    ac += x * wicT[(size_t)i * 512 + d];
  }
  size_t idx = (size_t)b * 512 + d;
  h[idx] = ah;
  c[idx] = ac;
  hb16[idx] = f2bf(ah);
}

// ---------- att1 via MFMA: [16384,512] = enc16[16384,128] x We16[512,128]^T ----------
__global__ __launch_bounds__(256) void k_att1m(const u16* __restrict__ enc16,
                                               const u16* __restrict__ We16,
                                               const float* __restrict__ b_enc,
                                               float* __restrict__ att1) {
  int w = threadIdx.x >> 6, lane = threadIdx.x & 63;
  int gw = blockIdx.x * 4 + w;
  int nt = gw & 15, mt = gw >> 4;
  int m0 = mt * 32, n0 = nt * 32;
  int rc = lane & 15, kb = lane >> 4;
  const bf16x8* a0 = (const bf16x8*)(enc16 + (size_t)(m0 + rc) * 128) + kb;
  const bf16x8* a1 = (const bf16x8*)(enc16 + (size_t)(m0 + 16 + rc) * 128) + kb;
  const bf16x8* b0 = (const bf16x8*)(We16 + (size_t)(n0 + rc) * 128) + kb;
  const bf16x8* b1 = (const bf16x8*)(We16 + (size_t)(n0 + 16 + rc) * 128) + kb;
  f32x4 z = {0.f, 0.f, 0.f, 0.f};
  f32x4 acc00 = z, acc01 = z, acc10 = z, acc11 = z;
#pragma unroll
  for (int kk = 0; kk < 4; kk++) {
    bf16x8 av0 = a0[kk * 4], av1 = a1[kk * 4];
    bf16x8 bv0 = b0[kk * 4], bv1 = b1[kk * 4];
    acc00 = __builtin_amdgcn_mfma_f32_16x16x32_bf16(av0, bv0, acc00, 0, 0, 0);
    acc01 = __builtin_amdgcn_mfma_f32_16x16x32_bf16(av0, bv1, acc01, 0, 0, 0);
    acc10 = __builtin_amdgcn_mfma_f32_16x16x32_bf16(av1, bv0, acc10, 0, 0, 0);
    acc11 = __builtin_amdgcn_mfma_f32_16x16x32_bf16(av1, bv1, acc11, 0, 0, 0);
  }
  int col = lane & 15, rbase = (lane >> 4) * 4;
#pragma unroll
  for (int r = 0; r < 4; r++) {
    int r0g = m0 + rbase + r;
    att1[(size_t)r0g * 512 + n0 + col]        = acc00[r] + b_enc[n0 + col];
    att1[(size_t)r0g * 512 + n0 + 16 + col]   = acc01[r] + b_enc[n0 + 16 + col];
    att1[(size_t)(r0g + 16) * 512 + n0 + col]      = acc10[r] + b_enc[n0 + col];
    att1[(size_t)(r0g + 16) * 512 + n0 + 16 + col] = acc11[r] + b_enc[n0 + 16 + col];
  }
}

// ================= persistent cooperative decode kernel =================
struct DecArgs {
  const float* att1;      // [16384,512]
  const u16*   Wdec16;    // [512,512]  (row a, col d)
  const float* b_dec;     // [512]
  const float* wfull;     // [512]
  const float* bfull;     // [1]
  const float* avf;       // [128,128,128]
  const float* maskf;     // [128,128]
  const float* wfbT;      // [512,128]
  const float* b_fb;      // [128]
  const float* rof;       // [128,256]
  const float* embt;      // [4000,300]
  const float* iemb;      // [300]
  const int*   lidx;      // [128,32]
  const int*   llen;      // [128]
  const u16*   WcatHi;    // [2048,1216] (n'=d*4+g)
  const u16*   WcatLo;
  const float* b_ih;      // [2048] (torch order g*512+d)
  const float* b_hh;
  const u16*   Wfc16;     // [4000,512]
  const float* b_fc;      // [4000]
  float* hbuf; float* cbuf; u16* hb16;
  u16* Xhi; u16* Xlo;     // [128,1216]
  float* att2s;           // [128,512]
  float* predsT;          // [32,128,4000]
  float* out_alpha;       // [128,32,128]
  float* out_pred;        // [128,4000,32]
  int direct;
};

__global__ __launch_bounds__(256) void k_decode(DecArgs A) {
  cg::grid_group grid = cg::this_grid();
  const int tid = threadIdx.x;
  const int w = tid >> 6, lane = tid & 63;
  const int gw = blockIdx.x * 4 + w;       // 0..1023
  const int rc = lane & 15, kb = lane >> 4;

  __shared__ float hs[512], a2s[512], wf[512];
  __shared__ float attk[128], alph[128], gts[128], awes[128];
  __shared__ float red[8];
  __shared__ float ttile[32][33];

  for (int t = 0; t < 32; ++t) {
    // ---------- P1: att2(t) [waves 0..255] + fc(t-1) [waves 256..1023] ----------
    if (gw < 256) {
      int mt = gw & 7, nt = gw >> 3;       // mt: b-tile (8), nt: a-tile (32)
      int m0 = mt * 16, n0 = nt * 16;
      const bf16x8* aP = (const bf16x8*)(A.hb16 + (size_t)(m0 + rc) * 512) + kb;
      const bf16x8* bP = (const bf16x8*)(A.Wdec16 + (size_t)(n0 + rc) * 512) + kb;
      f32x4 acc = {0.f, 0.f, 0.f, 0.f};
#pragma unroll
      for (int kk = 0; kk < 16; kk++)
        acc = __builtin_amdgcn_mfma_f32_16x16x32_bf16(aP[kk * 4], bP[kk * 4], acc, 0, 0, 0);
      int col = lane & 15, rb = (lane >> 4) * 4;
      float bias = A.b_dec[n0 + col];
#pragma unroll
      for (int r = 0; r < 4; r++)
        A.att2s[(size_t)(m0 + rb + r) * 512 + n0 + col] = acc[r] + bias;
    } else if (t > 0) {
      int tp = t - 1;
      for (int tile = gw - 256; tile < 2000; tile += 768) {
        int mt = tile & 7, nt = tile >> 3;
        int m0 = mt * 16, n0 = nt * 16;
        const bf16x8* aP = (const bf16x8*)(A.hb16 + (size_t)(m0 + rc) * 512) + kb;
        const bf16x8* bP = (const bf16x8*)(A.Wfc16 + (size_t)(n0 + rc) * 512) + kb;
        f32x4 acc = {0.f, 0.f, 0.f, 0.f};
#pragma unroll
        for (int kk = 0; kk < 16; kk++)
          acc = __builtin_amdgcn_mfma_f32_16x16x32_bf16(aP[kk * 4], bP[kk * 4], acc, 0, 0, 0);
        int col = lane & 15, rb = (lane >> 4) * 4;
        int v = n0 + col;
        float bias = A.b_fc[v];
#pragma unroll
        for (int r = 0; r < 4; r++) {
          int b = m0 + rb + r;
          float val = (tp < A.llen[b]) ? (acc[r] + bias) : 0.f;
          if (A.direct) A.out_pred[((size_t)b * 4000 + v) * 32 + tp] = val;
          else          A.predsT[((size_t)(tp * 128 + b)) * 4000 + v] = val;
        }
      }
    }
    grid.sync();

    // ---------- P2: per-b attention (blocks 0..127) ----------
    if (blockIdx.x < 128) {
      int b = blockIdx.x;
      hs[tid] = A.hbuf[(size_t)b * 512 + tid];
      hs[tid + 256] = A.hbuf[(size_t)b * 512 + 256 + tid];
      a2s[tid] = A.att2s[(size_t)b * 512 + tid];
      a2s[tid + 256] = A.att2s[(size_t)b * 512 + 256 + tid];
      wf[tid] = A.wfull[tid];
      wf[tid + 256] = A.wfull[tid + 256];
      __syncthreads();
      // att[k] = relu(att1+att2).wfull ; 2 threads per k
      {
        int k = tid >> 1, half = tid & 1;
        const float4* a1 = (const float4*)(A.att1 + ((size_t)(b * 128 + k)) * 512 + half * 256);
        float s = 0.f;
#pragma unroll 4
        for (int i = 0; i < 64; i++) {
          float4 v = a1[i];
          int base = half * 256 + i * 4;
          s += fmaxf(v.x + a2s[base + 0], 0.f) * wf[base + 0];
          s += fmaxf(v.y + a2s[base + 1], 0.f) * wf[base + 1];
          s += fmaxf(v.z + a2s[base + 2], 0.f) * wf[base + 2];
          s += fmaxf(v.w + a2s[base + 3], 0.f) * wf[base + 3];
        }
        s += __shfl_xor(s, 1);
        if (half == 0) attk[k] = s + A.bfull[0];
      }
      __syncthreads();
      // masked softmax over K=128 (threads 0..127 = waves 0,1)
      float mk = 0.f, av = 0.f;
      if (tid < 128) { mk = A.maskf[b * 128 + tid]; av = attk[tid]; }
      float nv = (tid < 128 && mk != 0.f) ? av : -INFINITY;
      float wm = nv;
#pragma unroll
      for (int o = 32; o > 0; o >>= 1) wm = fmaxf(wm, __shfl_xor(wm, o));
      if (tid < 128 && lane == 0) red[w] = wm;
      __syncthreads();
      float m = fmaxf(red[0], red[1]);
      float e = (tid < 128 && mk != 0.f) ? expf(av - m) : 0.f;
      float sr = e;
#pragma unroll
      for (int o = 32; o > 0; o >>= 1) sr += __shfl_xor(sr, o);
      if (tid < 128 && lane == 0) red[4 + w] = sr;
      __syncthreads();
      float dsum = red[4] + red[5];
      float alpha = (dsum > 0.f) ? e / fmaxf(dsum, 1e-30f) : 0.f;
      int active = t < A.llen[b];
      if (tid < 128) {
        alph[tid] = alpha;
        A.out_alpha[((size_t)b * 32 + t) * 128 + tid] = active ? alpha : 0.f;
      }
      __syncthreads();
      // awe[v] (tid<128) ; gate[v] (2 threads per v)
      float awe_v = 0.f;
      if (tid < 128) {
        for (int kk = 0; kk < 128; kk++)
          awe_v += alph[kk] * A.avf[((size_t)b * 128 + kk) * 128 + tid];
      }
      {
        int v = tid >> 1, half = tid & 1;
        float g = 0.f;
        for (int ii = 0; ii < 256; ii++) {
          int i = half * 256 + ii;
          g += hs[i] * A.wfbT[(size_t)i * 128 + v];
        }
        g += __shfl_xor(g, 1);
        if (half == 0) gts[v] = sigmoidf_(g + A.b_fb[v]);
      }
      __syncthreads();
      if (tid < 128) awes[tid] = awe_v * gts[tid];
      __syncthreads();
      // X row b -> bf16 hi/lo
      const float* esrc = (t == 0) ? A.iemb : (A.embt + (size_t)A.lidx[b * 32 + (t - 1)] * 300);
      for (int c = tid; c < XKP; c += 256) {
        float val;
        if (c < 300)       val = esrc[c];
        else if (c < 428)  val = awes[c - 300];
        else if (c < 684)  val = A.rof[(size_t)b * 256 + (c - 428)];
        else if (c < 1196) val = hs[c - 684];
        else               val = 0.f;
        u16 hi = f2bf(val);
        A.Xhi[(size_t)b * XKP + c] = hi;
        A.Xlo[(size_t)b * XKP + c] = f2bf(val - bf2f(hi));
      }
    }
    grid.sync();

    // ---------- P3: gates GEMM + LSTM (1024 waves = 1024 tiles) ----------
    {
      int mt = gw >> 7, ntp = gw & 127;
      int m0 = mt * 16, n0 = ntp * 16;
      const bf16x8* aHi = (const bf16x8*)(A.Xhi + (size_t)(m0 + rc) * XKP) + kb;
      const bf16x8* aLo = (const bf16x8*)(A.Xlo + (size_t)(m0 + rc) * XKP) + kb;
      const bf16x8* bHi = (const bf16x8*)(A.WcatHi + (size_t)(n0 + rc) * XKP) + kb;
      const bf16x8* bLo = (const bf16x8*)(A.WcatLo + (size_t)(n0 + rc) * XKP) + kb;
      f32x4 acc = {0.f, 0.f, 0.f, 0.f};
#pragma unroll 2
      for (int kk = 0; kk < 38; kk++) {
        bf16x8 ah = aHi[kk * 4], al = aLo[kk * 4];
        bf16x8 bh = bHi[kk * 4], bl = bLo[kk * 4];
        acc = __builtin_amdgcn_mfma_f32_16x16x32_bf16(ah, bh, acc, 0, 0, 0);
        acc = __builtin_amdgcn_mfma_f32_16x16x32_bf16(al, bh, acc, 0, 0, 0);
        acc = __builtin_amdgcn_mfma_f32_16x16x32_bf16(ah, bl, acc, 0, 0, 0);
      }
      // LSTM via intra-wave shfl: lanes 4q..4q+3 hold gates g=0..3 of d=ntp*4+q
      int col = lane & 15;
      int d = ntp * 4 + (col >> 2);
      int baseL = lane & ~3;
#pragma unroll
      for (int r = 0; r < 4; r++) {
        int b = m0 + (lane >> 4) * 4 + r;
        float g0 = __shfl(acc[r], baseL + 0);
        float g1 = __shfl(acc[r], baseL + 1);
        float g2 = __shfl(acc[r], baseL + 2);
        float g3 = __shfl(acc[r], baseL + 3);
        if ((lane & 3) == 0 && t < A.llen[b]) {
          float i_ = sigmoidf_(g0 + A.b_ih[d]        + A.b_hh[d]);
          float f_ = sigmoidf_(g1 + A.b_ih[512 + d]  + A.b_hh[512 + d]);
          float gg = tanhf   (g2 + A.b_ih[1024 + d] + A.b_hh[1024 + d]);
          float o_ = sigmoidf_(g3 + A.b_ih[1536 + d] + A.b_hh[1536 + d]);
          size_t idx = (size_t)b * 512 + d;
          float cn = f_ * A.cbuf[idx] + i_ * gg;
          float hn = o_ * tanhf(cn);
          A.cbuf[idx] = cn;
          A.hbuf[idx] = hn;
          A.hb16[idx] = f2bf(hn);
        }
      }
    }
    grid.sync();
  }

  // ---------- final fc(31) on all 1024 waves ----------
  {
    int tp = 31;
    for (int tile = gw; tile < 2000; tile += 1024) {
      int mt = tile & 7, nt = tile >> 3;
      int m0 = mt * 16, n0 = nt * 16;
      const bf16x8* aP = (const bf16x8*)(A.hb16 + (size_t)(m0 + rc) * 512) + kb;
      const bf16x8* bP = (const bf16x8*)(A.Wfc16 + (size_t)(n0 + rc) * 512) + kb;
      f32x4 acc = {0.f, 0.f, 0.f, 0.f};
#pragma unroll
      for (int kk = 0; kk < 16; kk++)
        acc = __builtin_amdgcn_mfma_f32_16x16x32_bf16(aP[kk * 4], bP[kk * 4], acc, 0, 0, 0);
      int col = lane & 15, rb = (lane >> 4) * 4;
      int v = n0 + col;
      float bias = A.b_fc[v];
#pragma unroll
      for (int r = 0; r < 4; r++) {
        int b = m0 + rb + r;
        float val = (tp < A.llen[b]) ? (acc[r] + bias) : 0.f;
        if (A.direct) A.out_pred[((size_t)b * 4000 + v) * 32 + tp] = val;
        else          A.predsT[((size_t)(tp * 128 + b)) * 4000 + v] = val;
      }
    }
  }
  if (!A.direct) {
    grid.sync();
    // ---------- transpose predsT[T,B,V] -> out[B,V,T] : 128*125 = 16000 tiles ----------
    for (int tile = blockIdx.x; tile < 16000; tile += 256) {
      int vt = tile >> 7, b = tile & 127;
      int v0 = vt * 32;
      int tx = tid & 31, ty = tid >> 5;   // ty 0..7
      __syncthreads();
      for (int i = 0; i < 32; i += 8) {
        int tt = ty + i;
        ttile[tt][tx] = A.predsT[((size_t)tt * 128 + b) * 4000 + v0 + tx];
      }
      __syncthreads();
      for (int i = 0; i < 32; i += 8) {
        int v = v0 + ty + i;
        A.out_pred[((size_t)b * 4000 + v) * 32 + tx] = ttile[tx][ty + i];
      }
    }
  }
}

extern "C" void kernel_launch(void* const* d_in, const int* in_sizes, int n_in,
                              void* d_out, int out_size, void* d_ws, size_t ws_size,
                              hipStream_t stream) {
  (void)in_sizes; (void)n_in; (void)out_size;
  const float* avf   = (const float*)d_in[0];
  const float* rof   = (const float*)d_in[1];
  const float* objs  = (const float*)d_in[2];
  const float* rcl   = (const float*)d_in[3];
  const float* avx   = (const float*)d_in[4];
  const int*   lidx  = (const int*)d_in[5];
  const int*   llen  = (const int*)d_in[6];
  const float* embt  = (const float*)d_in[7];
  const float* iemb  = (const float*)d_in[8];
  const float* W_enc = (const float*)d_in[9];
  const float* b_enc = (const float*)d_in[10];
  const float* W_dec = (const float*)d_in[11];
  const float* b_dec = (const float*)d_in[12];
  const float* wfull = (const float*)d_in[13];
  const float* bfull = (const float*)d_in[14];
  const float* W_ih  = (const float*)d_in[15];
  const float* b_ih  = (const float*)d_in[16];
  const float* W_hh  = (const float*)d_in[17];
  const float* b_hh  = (const float*)d_in[18];
  const float* W_inh = (const float*)d_in[19];
  const float* b_inh = (const float*)d_in[20];
  const float* W_inc = (const float*)d_in[21];
  const float* b_inc = (const float*)d_in[22];
  const float* W_fb  = (const float*)d_in[23];
  const float* b_fb  = (const float*)d_in[24];
  const float* W_fc  = (const float*)d_in[25];
  const float* b_fc  = (const float*)d_in[26];

  float* ws = (float*)d_ws;
  size_t f = 0;
  auto A8 = [&](size_t n) { size_t o = f; f += (n + 63) & ~(size_t)63; return o; };
  float* att1  = ws + A8((size_t)128 * 128 * 512);
  float* wihT  = ws + A8(384 * 512);
  float* wicT  = ws + A8(384 * 512);
  float* wfbT  = ws + A8(512 * 128);
  float* hbuf  = ws + A8(128 * 512);
  float* cbuf  = ws + A8(128 * 512);
  float* maskf = ws + A8(128 * 128);
  float* encm  = ws + A8(128 * 128);
  float* att2s = ws + A8(128 * 512);
  u16*   Xhi   = (u16*)(ws + A8((size_t)128 * XKP / 2));
  u16*   Xlo   = (u16*)(ws + A8((size_t)128 * XKP / 2));
  u16*   WcatHi= (u16*)(ws + A8((size_t)2048 * XKP / 2));
  u16*   WcatLo= (u16*)(ws + A8((size_t)2048 * XKP / 2));
  u16*   enc16 = (u16*)(ws + A8((size_t)128 * 128 * 128 / 2));
  u16*   We16  = (u16*)(ws + A8((size_t)512 * 128 / 2));
  u16*   Wdec16= (u16*)(ws + A8((size_t)512 * 512 / 2));
  u16*   Wfc16 = (u16*)(ws + A8((size_t)4000 * 512 / 2));
  u16*   hb16  = (u16*)(ws + A8((size_t)128 * 512 / 2));
  float* predsT= ws + A8((size_t)32 * 128 * 4000);
  bool useT = ws_size >= f * sizeof(float);

  float* out_pred  = (float*)d_out;
  float* out_alpha = out_pred + (size_t)16384000;
  float* out_mask  = out_alpha + (size_t)524288;

  // ---- setup ----
  k_transpose<<<dim3(12, 16), 256, 0, stream>>>(W_inh, wihT, 512, 384);
  k_transpose<<<dim3(12, 16), 256, 0, stream>>>(W_inc, wicT, 512, 384);
  k_transpose<<<dim3(16, 4),  256, 0, stream>>>(W_fb, wfbT, 128, 512);
  k_wcat_split<<<2048, 256, 0, stream>>>(W_ih, W_hh, WcatHi, WcatLo);
  k_cvt<<<2048, 256, 0, stream>>>(avf, enc16, 128 * 128 * 128);
  k_cvt<<<256,  256, 0, stream>>>(W_enc, We16, 512 * 128);
  k_cvt<<<512,  256, 0, stream>>>(W_dec, Wdec16, 512 * 512);
  k_cvt<<<2048, 256, 0, stream>>>(W_fc, Wfc16, 4000 * 512);
  k_mask<<<128, 128, 0, stream>>>(objs, rcl, avx, avf, maskf, encm, out_mask);
  k_init<<<128, 512, 0, stream>>>(encm, rof, wihT, wicT, b_inh, b_inc, hbuf, cbuf, hb16);
  k_att1m<<<2048, 256, 0, stream>>>(enc16, We16, b_enc, att1);

  // ---- persistent cooperative decode ----
  DecArgs da;
  da.att1 = att1; da.Wdec16 = Wdec16; da.b_dec = b_dec;
  da.wfull = wfull; da.bfull = bfull; da.avf = avf; da.maskf = maskf;
  da.wfbT = wfbT; da.b_fb = b_fb; da.rof = rof; da.embt = embt; da.iemb = iemb;
  da.lidx = lidx; da.llen = llen;
  da.WcatHi = WcatHi; da.WcatLo = WcatLo; da.b_ih = b_ih; da.b_hh = b_hh;
  da.Wfc16 = Wfc16; da.b_fc = b_fc;
  da.hbuf = hbuf; da.cbuf = cbuf; da.hb16 = hb16;
  da.Xhi = Xhi; da.Xlo = Xlo; da.att2s = att2s;
  da.predsT = predsT; da.out_alpha = out_alpha; da.out_pred = out_pred;
  da.direct = useT ? 0 : 1;
  void* kargs[] = { (void*)&da };
  hipLaunchCooperativeKernel((const void*)k_decode, dim3(256), dim3(256), kargs, 0, stream);
}

// Round 7
// 3189.916 us; speedup vs baseline: 1.5805x; 1.5805x over previous
//
#include <hip/hip_runtime.h>
#include <hip/hip_bf16.h>
#include <math.h>

#define XKP 1216

typedef unsigned short u16;
typedef short bf16x8 __attribute__((ext_vector_type(8)));
typedef float f32x4 __attribute__((ext_vector_type(4)));

static __device__ __forceinline__ float sigmoidf_(float x){ return 1.f/(1.f+expf(-x)); }
static __device__ __forceinline__ u16 f2bf(float x){ __hip_bfloat16 h = __float2bfloat16(x); return *reinterpret_cast<u16*>(&h); }
static __device__ __forceinline__ float bf2f(u16 u){ __hip_bfloat16 h; *reinterpret_cast<u16*>(&h) = u; return __bfloat162float(h); }

// ---------- lean grid barrier (256 blocks): cnt at bar[0], gen at bar[32] ----------
static __device__ __forceinline__ void gridbar(int* bar) {
  __syncthreads();
  if (threadIdx.x == 0) {
    int g = atomicAdd(&bar[32], 0);          // current generation (device-scope read)
    __threadfence();                          // release: my writes visible before arrival
    if (atomicAdd(&bar[0], 1) == 255) {
      atomicExch(&bar[0], 0);
      __threadfence();
      atomicAdd(&bar[32], 1);                // release generation
    } else {
      while (atomicAdd(&bar[32], 0) == g) { __builtin_amdgcn_s_sleep(2); }
    }
    __threadfence();                          // acquire: others' writes visible
  }
  __syncthreads();
}

// ---------- generic 32x32 tiled transpose ----------
__global__ __launch_bounds__(256) void k_transpose(const float* __restrict__ in,
                                                   float* __restrict__ out, int R, int C) {
  __shared__ float tile[32][33];
  int c0 = blockIdx.x * 32, r0 = blockIdx.y * 32;
  int tx = threadIdx.x & 31, ty = threadIdx.x >> 5;
  for (int i = 0; i < 32; i += 8) {
    int r = r0 + ty + i, c = c0 + tx;
    tile[ty + i][tx] = (r < R && c < C) ? in[(size_t)r * C + c] : 0.f;
  }
  __syncthreads();
  for (int i = 0; i < 32; i += 8) {
    int c = c0 + ty + i, r = r0 + tx;
    if (c < C && r < R) out[(size_t)c * R + r] = tile[tx][ty + i];
  }
}

// ---------- fp32 -> bf16 ----------
__global__ __launch_bounds__(256) void k_cvt(const float* __restrict__ in,
                                             u16* __restrict__ out, int n) {
  for (int i = blockIdx.x * 256 + threadIdx.x; i < n; i += gridDim.x * 256)
    out[i] = f2bf(in[i]);
}

// ---------- Wcat split hi/lo, gate-interleaved ----------
__global__ __launch_bounds__(256) void k_wcat_split(const float* __restrict__ W_ih,
                                                    const float* __restrict__ W_hh,
                                                    u16* __restrict__ Whi,
                                                    u16* __restrict__ Wlo) {
  int np = blockIdx.x;
  int d = np >> 2, g = np & 3;
  int j = g * 512 + d;
  for (int c = threadIdx.x; c < XKP; c += 256) {
    float v;
    if (c < 684)        v = W_ih[(size_t)j * 684 + c];
    else if (c < 1196)  v = W_hh[(size_t)j * 512 + (c - 684)];
    else                v = 0.f;
    u16 hi = f2bf(v);
    u16 lo = f2bf(v - bf2f(hi));
    Whi[(size_t)np * XKP + c] = hi;
    Wlo[(size_t)np * XKP + c] = lo;
  }
}

// ---------- objectness mask + top-16 + enc mean ----------
__global__ __launch_bounds__(128) void k_mask(const float* __restrict__ objs,
                                              const float* __restrict__ rcl,
                                              const float* __restrict__ avx,
                                              const float* __restrict__ enc,
                                              float* __restrict__ maskf,
                                              float* __restrict__ encmean,
                                              float* __restrict__ out_mask) {
  int b = blockIdx.x, k = threadIdx.x;
  __shared__ float dsh[128];
  __shared__ float maxd;
  float s0 = objs[(size_t)(b * 128 + k) * 2 + 0];
  float s1 = objs[(size_t)(b * 128 + k) * 2 + 1];
  float mx = fmaxf(s0, s1);
  float e0 = expf(s0 - mx), e1 = expf(s1 - mx);
  float p  = e1 / (e0 + e1);
  bool om  = p > 0.75f;
  float dx = rcl[b * 3 + 0] - avx[(size_t)(b * 128 + k) * 3 + 0];
  float dy = rcl[b * 3 + 1] - avx[(size_t)(b * 128 + k) * 3 + 1];
  float dz = rcl[b * 3 + 2] - avx[(size_t)(b * 128 + k) * 3 + 2];
  float dist = sqrtf(dx * dx + dy * dy + dz * dz);
  float dm = om ? dist : INFINITY;
  dsh[k] = dm;
  __syncthreads();
  float v = dm; int clt = 0, cle = 0;
  for (int j = 0; j < 128; j++) { float o = dsh[j]; clt += (o < v); cle += (o <= v); }
  if (clt < 16 && cle >= 16) maxd = v;
  __syncthreads();
  bool msk = om && (dm <= maxd);
  maskf[b * 128 + k]    = msk ? 1.f : 0.f;
  out_mask[b * 128 + k] = msk ? 1.f : 0.f;
  float s = 0.f;
  for (int kk = 0; kk < 128; kk++) s += enc[(size_t)(b * 128 + kk) * 128 + k];
  encmean[b * 128 + k] = s * (1.f / 128.f);
}

// ---------- h0/c0 init (+ zero the grid barrier) ----------
__global__ __launch_bounds__(512) void k_init(const float* __restrict__ encm,
                                              const float* __restrict__ rof,
                                              const float* __restrict__ wihT,
                                              const float* __restrict__ wicT,
                                              const float* __restrict__ bh,
                                              const float* __restrict__ bc,
                                              float* __restrict__ h, float* __restrict__ c,
                                              u16* __restrict__ hb16, int* __restrict__ bar) {
  int b = blockIdx.x, d = threadIdx.x;
  if (b == 0 && d < 64) bar[d] = 0;
  __shared__ float xin[384];
  if (d < 128) xin[d] = encm[b * 128 + d];
  else if (d < 384) xin[d] = rof[(size_t)b * 256 + (d - 128)];
  __syncthreads();
  float ah = bh[d], ac = bc[d];
  for (int i = 0; i < 384; i++) {
    float x = xin[i];
    ah += x * wihT[(size_t)i * 512 + d];
    ac += x * wicT[(size_t)i * 512 + d];
  }
  size_t idx = (size_t)b * 512 + d;
  h[idx] = ah;
  c[idx] = ac;
  hb16[idx] = f2bf(ah);
}

// ---------- att1 via MFMA ----------
__global__ __launch_bounds__(256) void k_att1m(const u16* __restrict__ enc16,
                                               const u16* __restrict__ We16,
                                               const float* __restrict__ b_enc,
                                               float* __restrict__ att1) {
  int w = threadIdx.x >> 6, lane = threadIdx.x & 63;
  int gw = blockIdx.x * 4 + w;
  int nt = gw & 15, mt = gw >> 4;
  int m0 = mt * 32, n0 = nt * 32;
  int rc = lane & 15, kb = lane >> 4;
  const bf16x8* a0 = (const bf16x8*)(enc16 + (size_t)(m0 + rc) * 128) + kb;
  const bf16x8* a1 = (const bf16x8*)(enc16 + (size_t)(m0 + 16 + rc) * 128) + kb;
  const bf16x8* b0 = (const bf16x8*)(We16 + (size_t)(n0 + rc) * 128) + kb;
  const bf16x8* b1 = (const bf16x8*)(We16 + (size_t)(n0 + 16 + rc) * 128) + kb;
  f32x4 z = {0.f, 0.f, 0.f, 0.f};
  f32x4 acc00 = z, acc01 = z, acc10 = z, acc11 = z;
#pragma unroll
  for (int kk = 0; kk < 4; kk++) {
    bf16x8 av0 = a0[kk * 4], av1 = a1[kk * 4];
    bf16x8 bv0 = b0[kk * 4], bv1 = b1[kk * 4];
    acc00 = __builtin_amdgcn_mfma_f32_16x16x32_bf16(av0, bv0, acc00, 0, 0, 0);
    acc01 = __builtin_amdgcn_mfma_f32_16x16x32_bf16(av0, bv1, acc01, 0, 0, 0);
    acc10 = __builtin_amdgcn_mfma_f32_16x16x32_bf16(av1, bv0, acc10, 0, 0, 0);
    acc11 = __builtin_amdgcn_mfma_f32_16x16x32_bf16(av1, bv1, acc11, 0, 0, 0);
  }
  int col = lane & 15, rbase = (lane >> 4) * 4;
#pragma unroll
  for (int r = 0; r < 4; r++) {
    int r0g = m0 + rbase + r;
    att1[(size_t)r0g * 512 + n0 + col]             = acc00[r] + b_enc[n0 + col];
    att1[(size_t)r0g * 512 + n0 + 16 + col]        = acc01[r] + b_enc[n0 + 16 + col];
    att1[(size_t)(r0g + 16) * 512 + n0 + col]      = acc10[r] + b_enc[n0 + col];
    att1[(size_t)(r0g + 16) * 512 + n0 + 16 + col] = acc11[r] + b_enc[n0 + 16 + col];
  }
}

// ================= persistent decode kernel (custom barrier) =================
struct DecArgs {
  const float* att1;
  const float* wdT;       // [512,512] (i,d)
  const float* b_dec;
  const float* wfull;
  const float* bfull;
  const float* avf;
  const float* maskf;
  const float* wfbT;      // [512,128]
  const float* b_fb;
  const float* rof;
  const float* embt;
  const float* iemb;
  const int*   lidx;
  const int*   llen;
  const u16*   WcatHi;
  const u16*   WcatLo;
  const float* b_ih;
  const float* b_hh;
  const u16*   Wfc16;
  const float* b_fc;
  float* hbuf; float* cbuf; u16* hb16;
  u16* Xhi; u16* Xlo;
  float* predsT;
  float* out_alpha;
  float* out_pred;
  int* bar;
  int direct;
};

static __device__ __forceinline__ void fc_tiles(const DecArgs& A, int tp, int fwid, int stride) {
  const int lane = threadIdx.x & 63;
  const int rc = lane & 15, kb = lane >> 4;
  for (int tile = fwid; tile < 2000; tile += stride) {
    int mt = tile & 7, nt = tile >> 3;
    int m0 = mt * 16, n0 = nt * 16;
    const bf16x8* aP = (const bf16x8*)(A.hb16 + (size_t)(m0 + rc) * 512) + kb;
    const bf16x8* bP = (const bf16x8*)(A.Wfc16 + (size_t)(n0 + rc) * 512) + kb;
    f32x4 acc = {0.f, 0.f, 0.f, 0.f};
#pragma unroll
    for (int kk = 0; kk < 16; kk++)
      acc = __builtin_amdgcn_mfma_f32_16x16x32_bf16(aP[kk * 4], bP[kk * 4], acc, 0, 0, 0);
    int col = lane & 15, rb = (lane >> 4) * 4;
    int v = n0 + col;
    float bias = A.b_fc[v];
#pragma unroll
    for (int r = 0; r < 4; r++) {
      int b = m0 + rb + r;
      float val = (tp < A.llen[b]) ? (acc[r] + bias) : 0.f;
      if (A.direct) A.out_pred[((size_t)b * 4000 + v) * 32 + tp] = val;
      else          A.predsT[((size_t)(tp * 128 + b)) * 4000 + v] = val;
    }
  }
}

__global__ __launch_bounds__(512) void k_decode(DecArgs A) {
  const int tid = threadIdx.x;
  const int w = tid >> 6, lane = tid & 63;

  __shared__ float hs[512], a2s[512], wf[512];
  __shared__ float attk[128], alph[128], gts[128], awes[128];
  __shared__ float red1[8], red2[8];
  __shared__ float ttile[32][33];

  for (int t = 0; t < 32; ++t) {
    // ---------- P2: attention (blocks 0..127)  ||  fc(t-1) (blocks 128..255) ----------
    if (blockIdx.x < 128) {
      int b = blockIdx.x;
      hs[tid] = A.hbuf[(size_t)b * 512 + tid];
      wf[tid] = A.wfull[tid];
      __syncthreads();
      // att2[a] = h . W_dec[a,:] + b_dec  (fp32, wdT[i,a])
      {
        float acc = A.b_dec[tid];
        for (int i = 0; i < 512; i++) acc += hs[i] * A.wdT[(size_t)i * 512 + tid];
        a2s[tid] = acc;
      }
      __syncthreads();
      // att[k] = relu(att1+att2).wfull  (4 threads per k)
      int k = tid >> 2, j = tid & 3;
      {
        const float4* a1 = (const float4*)(A.att1 + (size_t)(b * 128 + k) * 512 + j * 128);
        float s = 0.f;
#pragma unroll 4
        for (int i = 0; i < 32; i++) {
          float4 v = a1[i];
          int base = j * 128 + i * 4;
          s += fmaxf(v.x + a2s[base + 0], 0.f) * wf[base + 0];
          s += fmaxf(v.y + a2s[base + 1], 0.f) * wf[base + 1];
          s += fmaxf(v.z + a2s[base + 2], 0.f) * wf[base + 2];
          s += fmaxf(v.w + a2s[base + 3], 0.f) * wf[base + 3];
        }
        s += __shfl_xor(s, 1);
        s += __shfl_xor(s, 2);
        if (j == 0) attk[k] = s + A.bfull[0];
      }
      __syncthreads();
      // masked softmax over K=128 (tid<128)
      float mk = 0.f, av = 0.f;
      if (tid < 128) { mk = A.maskf[b * 128 + tid]; av = attk[tid]; }
      float nv = (tid < 128 && mk != 0.f) ? av : -INFINITY;
      float wm = nv;
#pragma unroll
      for (int o = 32; o > 0; o >>= 1) wm = fmaxf(wm, __shfl_xor(wm, o));
      if (tid < 128 && lane == 0) red1[w] = wm;
      __syncthreads();
      float m = fmaxf(red1[0], red1[1]);
      float e = (tid < 128 && mk != 0.f) ? expf(av - m) : 0.f;
      float sr = e;
#pragma unroll
      for (int o = 32; o > 0; o >>= 1) sr += __shfl_xor(sr, o);
      if (tid < 128 && lane == 0) red2[w] = sr;
      __syncthreads();
      float dsum = red2[0] + red2[1];
      float alpha = (dsum > 0.f) ? e / fmaxf(dsum, 1e-30f) : 0.f;
      int active = t < A.llen[b];
      if (tid < 128) {
        alph[tid] = alpha;
        A.out_alpha[((size_t)b * 32 + t) * 128 + tid] = active ? alpha : 0.f;
      }
      __syncthreads();
      // awe[v] (tid<128) ; gate[v] (4 threads per v)
      float awe_v = 0.f;
      if (tid < 128) {
        for (int kk = 0; kk < 128; kk++)
          awe_v += alph[kk] * A.avf[((size_t)b * 128 + kk) * 128 + tid];
      }
      {
        int v = tid >> 2;
        float g = 0.f;
        for (int ii = 0; ii < 128; ii++) {
          int i = j * 128 + ii;
          g += hs[i] * A.wfbT[(size_t)i * 128 + v];
        }
        g += __shfl_xor(g, 1);
        g += __shfl_xor(g, 2);
        if (j == 0) gts[v] = sigmoidf_(g + A.b_fb[v]);
      }
      __syncthreads();
      if (tid < 128) awes[tid] = awe_v * gts[tid];
      __syncthreads();
      // X row b -> bf16 hi/lo
      const float* esrc = (t == 0) ? A.iemb : (A.embt + (size_t)A.lidx[b * 32 + (t - 1)] * 300);
      for (int c = tid; c < XKP; c += 512) {
        float val;
        if (c < 300)       val = esrc[c];
        else if (c < 428)  val = awes[c - 300];
        else if (c < 684)  val = A.rof[(size_t)b * 256 + (c - 428)];
        else if (c < 1196) val = hs[c - 684];
        else               val = 0.f;
        u16 hi = f2bf(val);
        A.Xhi[(size_t)b * XKP + c] = hi;
        A.Xlo[(size_t)b * XKP + c] = f2bf(val - bf2f(hi));
      }
    } else if (t > 0) {
      fc_tiles(A, t - 1, (blockIdx.x - 128) * 8 + w, 1024);
    }
    gridbar(A.bar);

    // ---------- P3: gates GEMM + LSTM (waves gwid 0..1023) ----------
    {
      int gwid = blockIdx.x * 8 + w;
      if (gwid < 1024) {
        int mt = gwid >> 7, ntp = gwid & 127;
        int m0 = mt * 16, n0 = ntp * 16;
        int rc = lane & 15, kb = lane >> 4;
        const bf16x8* aHi = (const bf16x8*)(A.Xhi + (size_t)(m0 + rc) * XKP) + kb;
        const bf16x8* aLo = (const bf16x8*)(A.Xlo + (size_t)(m0 + rc) * XKP) + kb;
        const bf16x8* bHi = (const bf16x8*)(A.WcatHi + (size_t)(n0 + rc) * XKP) + kb;
        const bf16x8* bLo = (const bf16x8*)(A.WcatLo + (size_t)(n0 + rc) * XKP) + kb;
        f32x4 acc = {0.f, 0.f, 0.f, 0.f};
#pragma unroll 2
        for (int kk = 0; kk < 38; kk++) {
          bf16x8 ah = aHi[kk * 4], al = aLo[kk * 4];
          bf16x8 bh = bHi[kk * 4], bl = bLo[kk * 4];
          acc = __builtin_amdgcn_mfma_f32_16x16x32_bf16(ah, bh, acc, 0, 0, 0);
          acc = __builtin_amdgcn_mfma_f32_16x16x32_bf16(al, bh, acc, 0, 0, 0);
          acc = __builtin_amdgcn_mfma_f32_16x16x32_bf16(ah, bl, acc, 0, 0, 0);
        }
        // LSTM via intra-wave shfl: lanes 4q..4q+3 hold gates 0..3 of d=ntp*4+q
        int col = lane & 15;
        int d = ntp * 4 + (col >> 2);
        int baseL = lane & ~3;
#pragma unroll
        for (int r = 0; r < 4; r++) {
          int b = m0 + (lane >> 4) * 4 + r;
          float g0 = __shfl(acc[r], baseL + 0);
          float g1 = __shfl(acc[r], baseL + 1);
          float g2 = __shfl(acc[r], baseL + 2);
          float g3 = __shfl(acc[r], baseL + 3);
          if ((lane & 3) == 0 && t < A.llen[b]) {
            float i_ = sigmoidf_(g0 + A.b_ih[d]        + A.b_hh[d]);
            float f_ = sigmoidf_(g1 + A.b_ih[512 + d]  + A.b_hh[512 + d]);
            float gg = tanhf   (g2 + A.b_ih[1024 + d] + A.b_hh[1024 + d]);
            float o_ = sigmoidf_(g3 + A.b_ih[1536 + d] + A.b_hh[1536 + d]);
            size_t idx = (size_t)b * 512 + d;
            float cn = f_ * A.cbuf[idx] + i_ * gg;
            float hn = o_ * tanhf(cn);
            A.cbuf[idx] = cn;
            A.hbuf[idx] = hn;
            A.hb16[idx] = f2bf(hn);
          }
        }
      }
    }
    gridbar(A.bar);
  }

  // ---------- fc(31): all 2048 waves ----------
  fc_tiles(A, 31, blockIdx.x * 8 + w, 2048);

  if (!A.direct) {
    gridbar(A.bar);
    // transpose predsT[T,B,V] -> out[B,V,T]
    for (int tile = blockIdx.x; tile < 16000; tile += 256) {
      int vt = tile >> 7, b = tile & 127;
      int v0 = vt * 32;
      int tx = tid & 31, ty = tid >> 5;   // ty 0..15
      __syncthreads();
      for (int i = 0; i < 32; i += 16) {
        int tt = ty + i;
        ttile[tt][tx] = A.predsT[((size_t)tt * 128 + b) * 4000 + v0 + tx];
      }
      __syncthreads();
      for (int i = 0; i < 32; i += 16) {
        int v = v0 + ty + i;
        A.out_pred[((size_t)b * 4000 + v) * 32 + tx] = ttile[tx][ty + i];
      }
    }
  }
}

extern "C" void kernel_launch(void* const* d_in, const int* in_sizes, int n_in,
                              void* d_out, int out_size, void* d_ws, size_t ws_size,
                              hipStream_t stream) {
  (void)in_sizes; (void)n_in; (void)out_size;
  const float* avf   = (const float*)d_in[0];
  const float* rof   = (const float*)d_in[1];
  const float* objs  = (const float*)d_in[2];
  const float* rcl   = (const float*)d_in[3];
  const float* avx   = (const float*)d_in[4];
  const int*   lidx  = (const int*)d_in[5];
  const int*   llen  = (const int*)d_in[6];
  const float* embt  = (const float*)d_in[7];
  const float* iemb  = (const float*)d_in[8];
  const float* W_enc = (const float*)d_in[9];
  const float* b_enc = (const float*)d_in[10];
  const float* W_dec = (const float*)d_in[11];
  const float* b_dec = (const float*)d_in[12];
  const float* wfull = (const float*)d_in[13];
  const float* bfull = (const float*)d_in[14];
  const float* W_ih  = (const float*)d_in[15];
  const float* b_ih  = (const float*)d_in[16];
  const float* W_hh  = (const float*)d_in[17];
  const float* b_hh  = (const float*)d_in[18];
  const float* W_inh = (const float*)d_in[19];
  const float* b_inh = (const float*)d_in[20];
  const float* W_inc = (const float*)d_in[21];
  const float* b_inc = (const float*)d_in[22];
  const float* W_fb  = (const float*)d_in[23];
  const float* b_fb  = (const float*)d_in[24];
  const float* W_fc  = (const float*)d_in[25];
  const float* b_fc  = (const float*)d_in[26];

  float* ws = (float*)d_ws;
  size_t f = 0;
  auto A8 = [&](size_t n) { size_t o = f; f += (n + 63) & ~(size_t)63; return o; };
  float* att1  = ws + A8((size_t)128 * 128 * 512);
  float* wdT   = ws + A8(512 * 512);
  float* wihT  = ws + A8(384 * 512);
  float* wicT  = ws + A8(384 * 512);
  float* wfbT  = ws + A8(512 * 128);
  float* hbuf  = ws + A8(128 * 512);
  float* cbuf  = ws + A8(128 * 512);
  float* maskf = ws + A8(128 * 128);
  float* encm  = ws + A8(128 * 128);
  int*   bar   = (int*)(ws + A8(64));
  u16*   Xhi   = (u16*)(ws + A8((size_t)128 * XKP / 2));
  u16*   Xlo   = (u16*)(ws + A8((size_t)128 * XKP / 2));
  u16*   WcatHi= (u16*)(ws + A8((size_t)2048 * XKP / 2));
  u16*   WcatLo= (u16*)(ws + A8((size_t)2048 * XKP / 2));
  u16*   enc16 = (u16*)(ws + A8((size_t)128 * 128 * 128 / 2));
  u16*   We16  = (u16*)(ws + A8((size_t)512 * 128 / 2));
  u16*   Wfc16 = (u16*)(ws + A8((size_t)4000 * 512 / 2));
  u16*   hb16  = (u16*)(ws + A8((size_t)128 * 512 / 2));
  float* predsT= ws + A8((size_t)32 * 128 * 4000);
  bool useT = ws_size >= f * sizeof(float);

  float* out_pred  = (float*)d_out;
  float* out_alpha = out_pred + (size_t)16384000;
  float* out_mask  = out_alpha + (size_t)524288;

  // ---- setup ----
  k_transpose<<<dim3(16, 16), 256, 0, stream>>>(W_dec, wdT, 512, 512);
  k_transpose<<<dim3(12, 16), 256, 0, stream>>>(W_inh, wihT, 512, 384);
  k_transpose<<<dim3(12, 16), 256, 0, stream>>>(W_inc, wicT, 512, 384);
  k_transpose<<<dim3(16, 4),  256, 0, stream>>>(W_fb, wfbT, 128, 512);
  k_wcat_split<<<2048, 256, 0, stream>>>(W_ih, W_hh, WcatHi, WcatLo);
  k_cvt<<<2048, 256, 0, stream>>>(avf, enc16, 128 * 128 * 128);
  k_cvt<<<256,  256, 0, stream>>>(W_enc, We16, 512 * 128);
  k_cvt<<<2048, 256, 0, stream>>>(W_fc, Wfc16, 4000 * 512);
  k_mask<<<128, 128, 0, stream>>>(objs, rcl, avx, avf, maskf, encm, out_mask);
  k_init<<<128, 512, 0, stream>>>(encm, rof, wihT, wicT, b_inh, b_inc, hbuf, cbuf, hb16, bar);
  k_att1m<<<2048, 256, 0, stream>>>(enc16, We16, b_enc, att1);

  // ---- persistent decode (cooperative for co-residency; custom barrier inside) ----
  DecArgs da;
  da.att1 = att1; da.wdT = wdT; da.b_dec = b_dec;
  da.wfull = wfull; da.bfull = bfull; da.avf = avf; da.maskf = maskf;
  da.wfbT = wfbT; da.b_fb = b_fb; da.rof = rof; da.embt = embt; da.iemb = iemb;
  da.lidx = lidx; da.llen = llen;
  da.WcatHi = WcatHi; da.WcatLo = WcatLo; da.b_ih = b_ih; da.b_hh = b_hh;
  da.Wfc16 = Wfc16; da.b_fc = b_fc;
  da.hbuf = hbuf; da.cbuf = cbuf; da.hb16 = hb16;
  da.Xhi = Xhi; da.Xlo = Xlo;
  da.predsT = predsT; da.out_alpha = out_alpha; da.out_pred = out_pred;
  da.bar = bar;
  da.direct = useT ? 0 : 1;
  void* kargs[] = { (void*)&da };
  hipLaunchCooperativeKernel((const void*)k_decode, dim3(256), dim3(512), kargs, 0, stream);
}